// Round 1
// baseline (631.024 us; speedup 1.0000x reference)
//
#include <hip/hip_runtime.h>

#define N_NODES 262144
#define BM 32

typedef short s16x8 __attribute__((ext_vector_type(8)));
typedef float f32x4 __attribute__((ext_vector_type(4)));

static __device__ __forceinline__ unsigned short f2bf(float f) {
  union { float f; unsigned u; } v; v.f = f;
  unsigned u = v.u;
  u += 0x7FFFu + ((u >> 16) & 1u);   // round-to-nearest-even
  return (unsigned short)(u >> 16);
}

static __device__ __forceinline__ float fsig(float x) {
  return __builtin_amdgcn_rcpf(1.0f + __expf(-x));
}
static __device__ __forceinline__ float ftanh(float x) {
  return 2.0f * __builtin_amdgcn_rcpf(1.0f + __expf(-2.0f * x)) - 1.0f;
}

// One-shot weight prep: fp32 -> bf16 copies of W_hid / W_ih / W_hh, plus b_ih+b_hh.
__global__ void prep_kernel(const float* __restrict__ Wh, const float* __restrict__ Wih,
                            const float* __restrict__ Whh, const float* __restrict__ bih,
                            const float* __restrict__ bhh,
                            unsigned short* __restrict__ oWh, unsigned short* __restrict__ oWih,
                            unsigned short* __restrict__ oWhh, float* __restrict__ oBias) {
  int t = blockIdx.x * 256 + threadIdx.x;
  if (t < 32768) oWh[t] = f2bf(Wh[t]);
  if (t < 65536) { oWih[t] = f2bf(Wih[t]); oWhh[t] = f2bf(Whh[t]); }
  if (t < 512) oBias[t] = bih[t] + bhh[t];
}

// swizzled LDS byte offset: row m (512B rows), XOR bits 4..6 with m&7 (G4 fix)
#define SWZ(m, b) (((m) * 512 + (b)) ^ (((m) & 7) << 4))

__global__ __launch_bounds__(256, 2) void node_rnn_kernel(
    const float* __restrict__ Hv, const float* __restrict__ hvv,
    const float* __restrict__ xv, const float* __restrict__ hvp,
    const float* __restrict__ cvp, const int* __restrict__ tsm,
    const float* __restrict__ Wpos, const float* __restrict__ bpos,
    const float* __restrict__ bhid,
    const unsigned short* __restrict__ Whb,
    const unsigned short* __restrict__ Wihb,
    const unsigned short* __restrict__ Whhb,
    const float* __restrict__ biasg,
    float* __restrict__ hvo, float* __restrict__ cvo)
{
  // A2: BM x 256 bf16 = [e_v(64) | a_v(64) | hv(128)] per node row
  __shared__ unsigned short A2[BM * 256];
  char* A2b = (char*)A2;

  const int tid = threadIdx.x;
  const int w   = tid >> 6;    // wave 0..3
  const int l   = tid & 63;
  const int l15 = l & 15;
  const int lk  = l >> 4;      // k-group 0..3
  const int node0 = blockIdx.x * BM;

  // ---- Phase 0a: e_v = relu(xv @ Wpos^T + bpos) -> A2 cols [0,64)
  for (int p = tid; p < BM * 64; p += 256) {
    int m = p >> 6, j = p & 63;
    float x0 = xv[(size_t)(node0 + m) * 2 + 0];
    float x1 = xv[(size_t)(node0 + m) * 2 + 1];
    float e = fmaxf(x0 * Wpos[j * 2 + 0] + x1 * Wpos[j * 2 + 1] + bpos[j], 0.0f);
    *(unsigned short*)(A2b + SWZ(m, j * 2)) = f2bf(e);
  }
  // ---- Phase 0b: hv_tm1 -> bf16 -> A2 cols [128,256)
  for (int p = tid; p < BM * 32; p += 256) {
    int m = p >> 5, c4 = p & 31;
    f32x4 v = *(const f32x4*)(hvp + (size_t)(node0 + m) * 128 + c4 * 4);
    unsigned u0 = (unsigned)f2bf(v.x) | ((unsigned)f2bf(v.y) << 16);
    unsigned u1 = (unsigned)f2bf(v.z) | ((unsigned)f2bf(v.w) << 16);
    unsigned long long u = (unsigned long long)u0 | ((unsigned long long)u1 << 32);
    *(unsigned long long*)(A2b + SWZ(m, 256 + c4 * 8)) = u;
  }

  // ---- Phase 1: a_v = relu([hvv|Hv] @ Wh^T + bhid) -> A2 cols [64,128)
  {
    f32x4 acc[2] = {f32x4{0.f,0.f,0.f,0.f}, f32x4{0.f,0.f,0.f,0.f}};
    const unsigned short* bptr = Whb + (size_t)(16 * w + l15) * 512 + lk * 8;
    for (int k0 = 0; k0 < 512; k0 += 32) {
      s16x8 bf = *(const s16x8*)(bptr + k0);
      int kk = k0 + lk * 8;
      const float* base = (kk < 256) ? hvv : Hv;
      int kc = (kk < 256) ? kk : (kk - 256);
#pragma unroll
      for (int mi = 0; mi < 2; ++mi) {
        int m = mi * 16 + l15;
        const float* src = base + (size_t)(node0 + m) * 256 + kc;
        f32x4 a0 = *(const f32x4*)src;
        f32x4 a1 = *(const f32x4*)(src + 4);
        s16x8 af;
        af[0]=(short)f2bf(a0.x); af[1]=(short)f2bf(a0.y);
        af[2]=(short)f2bf(a0.z); af[3]=(short)f2bf(a0.w);
        af[4]=(short)f2bf(a1.x); af[5]=(short)f2bf(a1.y);
        af[6]=(short)f2bf(a1.z); af[7]=(short)f2bf(a1.w);
        acc[mi] = __builtin_amdgcn_mfma_f32_16x16x32_bf16(af, bf, acc[mi], 0, 0, 0);
      }
    }
    float bb = bhid[16 * w + l15];
    int c = 64 + 16 * w + l15;
#pragma unroll
    for (int mi = 0; mi < 2; ++mi) {
#pragma unroll
      for (int r = 0; r < 4; ++r) {
        int m = mi * 16 + lk * 4 + r;
        float av = fmaxf(acc[mi][r] + bb, 0.0f);
        *(unsigned short*)(A2b + SWZ(m, c * 2)) = f2bf(av);
      }
    }
  }
  __syncthreads();

  // ---- Phase 2: gates = A2(32x256) @ [Wih;Whh]^T(256x512), wave w takes n-tiles 16w+64j
  f32x4 acc2[2][8];
#pragma unroll
  for (int mi = 0; mi < 2; ++mi)
#pragma unroll
    for (int j = 0; j < 8; ++j) acc2[mi][j] = f32x4{0.f,0.f,0.f,0.f};

#pragma unroll
  for (int kk = 0; kk < 8; ++kk) {
    int k0 = kk * 32;
    s16x8 a[2];
#pragma unroll
    for (int mi = 0; mi < 2; ++mi) {
      int m = mi * 16 + l15;
      a[mi] = *(const s16x8*)(A2b + SWZ(m, k0 * 2 + lk * 16));
    }
    const unsigned short* wsrc = (k0 < 128) ? (Wihb + k0 + lk * 8)
                                            : (Whhb + (k0 - 128) + lk * 8);
#pragma unroll
    for (int j = 0; j < 8; ++j) {
      size_t n = 16 * w + 64 * j + l15;
      s16x8 bf = *(const s16x8*)(wsrc + n * 128);
      acc2[0][j] = __builtin_amdgcn_mfma_f32_16x16x32_bf16(a[0], bf, acc2[0][j], 0, 0, 0);
      acc2[1][j] = __builtin_amdgcn_mfma_f32_16x16x32_bf16(a[1], bf, acc2[1][j], 0, 0, 0);
    }
  }

  // ---- Phase 3: LSTM pointwise + mask select. acc2[mi][j]: gate=j>>1, d-half=j&1
  float bs[8];
#pragma unroll
  for (int j = 0; j < 8; ++j) bs[j] = biasg[64 * j + 16 * w + l15];

#pragma unroll
  for (int mi = 0; mi < 2; ++mi) {
#pragma unroll
    for (int r = 0; r < 4; ++r) {
      int m = mi * 16 + lk * 4 + r;
      size_t node = (size_t)node0 + m;
      int act = tsm[node];
#pragma unroll
      for (int half = 0; half < 2; ++half) {
        int d = 16 * w + 64 * half + l15;
        float gi = acc2[mi][0 + half][r] + bs[0 + half];
        float gf = acc2[mi][2 + half][r] + bs[2 + half];
        float gg = acc2[mi][4 + half][r] + bs[4 + half];
        float go = acc2[mi][6 + half][r] + bs[6 + half];
        float i_ = fsig(gi), f_ = fsig(gf), o_ = fsig(go);
        float g_ = ftanh(gg);
        float co = cvp[node * 128 + d];
        float ho = hvp[node * 128 + d];
        float cn = f_ * co + i_ * g_;
        float hn = o_ * ftanh(cn);
        hvo[node * 128 + d] = act ? hn : ho;
        cvo[node * 128 + d] = act ? cn : co;
      }
    }
  }
}

extern "C" void kernel_launch(void* const* d_in, const int* in_sizes, int n_in,
                              void* d_out, int out_size, void* d_ws, size_t ws_size,
                              hipStream_t stream) {
  const float* Hv   = (const float*)d_in[0];
  const float* hvv  = (const float*)d_in[1];
  const float* xv   = (const float*)d_in[2];
  const float* hvp  = (const float*)d_in[3];
  const float* cvp  = (const float*)d_in[4];
  const int*   tsm  = (const int*)d_in[5];
  const float* Wpos = (const float*)d_in[6];
  const float* bpos = (const float*)d_in[7];
  const float* Whid = (const float*)d_in[8];
  const float* bhid = (const float*)d_in[9];
  const float* Wih  = (const float*)d_in[10];
  const float* bih  = (const float*)d_in[11];
  const float* Whh  = (const float*)d_in[12];
  const float* bhh  = (const float*)d_in[13];

  unsigned short* wsWh  = (unsigned short*)d_ws;   // 32768 bf16
  unsigned short* wsWih = wsWh + 32768;            // 65536 bf16
  unsigned short* wsWhh = wsWih + 65536;           // 65536 bf16
  float* wsBias = (float*)(wsWhh + 65536);         // 512 f32

  prep_kernel<<<256, 256, 0, stream>>>(Whid, Wih, Whh, bih, bhh,
                                       wsWh, wsWih, wsWhh, wsBias);

  float* hvo = (float*)d_out;
  float* cvo = hvo + (size_t)N_NODES * 128;
  node_rnn_kernel<<<N_NODES / BM, 256, 0, stream>>>(
      Hv, hvv, xv, hvp, cvp, tsm, Wpos, bpos, bhid,
      wsWh, wsWih, wsWhh, wsBias, hvo, cvo);
}

// Round 2
// 284.550 us; speedup vs baseline: 2.2176x; 2.2176x over previous
//
#include <hip/hip_runtime.h>

#define N_NODES 262144
#define BM 64
#define NTHREADS 512

typedef short s16x8 __attribute__((ext_vector_type(8)));
typedef float f32x4 __attribute__((ext_vector_type(4)));

static __device__ __forceinline__ unsigned short f2bf(float f) {
  union { float f; unsigned u; } v; v.f = f;
  unsigned u = v.u;
  u += 0x7FFFu + ((u >> 16) & 1u);   // round-to-nearest-even
  return (unsigned short)(u >> 16);
}

static __device__ __forceinline__ unsigned long long pack4bf(f32x4 v) {
  unsigned u0 = (unsigned)f2bf(v.x) | ((unsigned)f2bf(v.y) << 16);
  unsigned u1 = (unsigned)f2bf(v.z) | ((unsigned)f2bf(v.w) << 16);
  return (unsigned long long)u0 | ((unsigned long long)u1 << 32);
}

static __device__ __forceinline__ float fsig(float x) {
  return __builtin_amdgcn_rcpf(1.0f + __expf(-x));
}
static __device__ __forceinline__ float ftanh(float x) {
  return 2.0f * __builtin_amdgcn_rcpf(1.0f + __expf(-2.0f * x)) - 1.0f;
}

// Weight prep:
//  Wh2[kb][n][ki] (16 x 64 x 32 bf16)  = W_hid[n][kb*32+ki]           (coalesced B-frag loads)
//  W2 [kb][n][ki] ( 8 x 512 x 32 bf16) = k<128 ? W_ih[n][k] : W_hh[n][k-128], k = kb*32+ki
//  biasg[512] = b_ih + b_hh
__global__ void prep_kernel(const float* __restrict__ Whid, const float* __restrict__ Wih,
                            const float* __restrict__ Whh, const float* __restrict__ bih,
                            const float* __restrict__ bhh,
                            unsigned short* __restrict__ oWh2, unsigned short* __restrict__ oW2,
                            float* __restrict__ oBias) {
  int t = blockIdx.x * 256 + threadIdx.x;
  if (t < 32768) {
    int kb = t >> 11, n = (t >> 5) & 63, ki = t & 31;
    oWh2[t] = f2bf(Whid[n * 512 + kb * 32 + ki]);
  }
  if (t < 131072) {
    int kb = t >> 14, n = (t >> 5) & 511, ki = t & 31;
    int k = kb * 32 + ki;
    float v = (k < 128) ? Wih[n * 128 + k] : Whh[n * 128 + (k - 128)];
    oW2[t] = f2bf(v);
  }
  if (t < 512) oBias[t] = bih[t] + bhh[t];
}

// Astage: 64 rows x 512 bf16 (1024B rows). SWZA spreads 16 strided rows over 8 16B slots.
#define SWZA(m, b) ((((m) * 1024) + (b)) ^ (((m) & 7) << 4))
// A2: 64 rows x 256 bf16 (512B rows) = [e_v(64) | a_v(64) | hv(128)]. Aliases Astage[0:32KB].
#define SWZ2(m, b) ((((m) * 512) + (b)) ^ (((m) & 7) << 4))

__global__ __launch_bounds__(NTHREADS, 4) void node_rnn_kernel(
    const float* __restrict__ Hv, const float* __restrict__ hvv,
    const float* __restrict__ xv, const float* __restrict__ hvp,
    const float* __restrict__ cvp, const int* __restrict__ tsm,
    const float* __restrict__ Wpos, const float* __restrict__ bpos,
    const float* __restrict__ bhid,
    const unsigned short* __restrict__ Wh2,
    const unsigned short* __restrict__ W2,
    const float* __restrict__ biasg,
    float* __restrict__ hvo, float* __restrict__ cvo)
{
  __shared__ __align__(16) char lds[65536];

  const int tid = threadIdx.x;
  const int w   = tid >> 6;      // wave 0..7
  const int l   = tid & 63;
  const int l15 = l & 15;
  const int lk  = l >> 4;        // k-group 0..3
  const int wr  = w >> 2;        // phase-1 m-half
  const int wc  = w & 3;         // phase-1 n-slice (16 cols)
  const int node0 = blockIdx.x * BM;

  // ---- Stage [hvv|Hv] (64 x 512 f32) -> bf16 Astage, coalesced f32x4, converted ONCE
#pragma unroll
  for (int it = 0; it < 16; ++it) {
    int p = tid + it * NTHREADS;            // 0..8191 : 64 rows x 128 f32x4-chunks
    int m = p >> 7, ch = p & 127;
    const float* src = (ch < 64) ? (hvv + (size_t)(node0 + m) * 256 + ch * 4)
                                 : (Hv  + (size_t)(node0 + m) * 256 + (ch - 64) * 4);
    f32x4 v = *(const f32x4*)src;
    *(unsigned long long*)(lds + SWZA(m, ch * 8)) = pack4bf(v);
  }

  // ---- Prefetch+compute e_v into regs (overlaps latency with phase 1)
  float ev[8];
#pragma unroll
  for (int it = 0; it < 8; ++it) {
    int p = tid + it * NTHREADS;            // 64 rows x 64 cols
    int m = p >> 6, j = p & 63;
    float x0 = xv[(size_t)(node0 + m) * 2 + 0];
    float x1 = xv[(size_t)(node0 + m) * 2 + 1];
    ev[it] = fmaxf(x0 * Wpos[j * 2 + 0] + x1 * Wpos[j * 2 + 1] + bpos[j], 0.0f);
  }
  // ---- Prefetch hv_tm1 chunks (bf16-packed after the barrier)
  f32x4 hvc[4];
#pragma unroll
  for (int it = 0; it < 4; ++it) {
    int p = tid + it * NTHREADS;            // 64 rows x 32 f32x4-chunks
    int m = p >> 5, c4 = p & 31;
    hvc[it] = *(const f32x4*)(hvp + (size_t)(node0 + m) * 128 + c4 * 4);
  }

  __syncthreads();

  // ---- Phase 1: a_v = relu([hvv|Hv] @ Wh^T + bhid); wave (wr,wc): rows wr*32+32, cols wc*16+16
  f32x4 acc[2] = {f32x4{0.f,0.f,0.f,0.f}, f32x4{0.f,0.f,0.f,0.f}};
  {
    const char* whb = (const char*)Wh2 + (wc * 16 + l15) * 64 + lk * 16;
#pragma unroll
    for (int ks = 0; ks < 16; ++ks) {
      s16x8 bf = *(const s16x8*)(whb + ks * 4096);
#pragma unroll
      for (int mi = 0; mi < 2; ++mi) {
        int m = wr * 32 + mi * 16 + l15;
        s16x8 af = *(const s16x8*)(lds + SWZA(m, ks * 64 + lk * 16));
        acc[mi] = __builtin_amdgcn_mfma_f32_16x16x32_bf16(af, bf, acc[mi], 0, 0, 0);
      }
    }
  }

  __syncthreads();   // all Astage reads done; safe to overwrite with A2

  // ---- Build A2 = [e_v | a_v | hv] bf16
#pragma unroll
  for (int it = 0; it < 8; ++it) {
    int p = tid + it * NTHREADS;
    int m = p >> 6, j = p & 63;
    *(unsigned short*)(lds + SWZ2(m, j * 2)) = f2bf(ev[it]);
  }
#pragma unroll
  for (int it = 0; it < 4; ++it) {
    int p = tid + it * NTHREADS;
    int m = p >> 5, c4 = p & 31;
    *(unsigned long long*)(lds + SWZ2(m, 256 + c4 * 8)) = pack4bf(hvc[it]);
  }
  {
    float bb = bhid[wc * 16 + l15];
    int cb = (64 + wc * 16 + l15) * 2;
#pragma unroll
    for (int mi = 0; mi < 2; ++mi) {
#pragma unroll
      for (int r = 0; r < 4; ++r) {
        int m = wr * 32 + mi * 16 + lk * 4 + r;
        float av = fmaxf(acc[mi][r] + bb, 0.0f);
        *(unsigned short*)(lds + SWZ2(m, cb)) = f2bf(av);
      }
    }
  }
  __syncthreads();

  // ---- Phase 2: gates = A2(64x256) @ [Wih;Whh]^T; wave w owns d-slice [16w,16w+16) of all 4 gates
  f32x4 acc2[4][4];
#pragma unroll
  for (int mi = 0; mi < 4; ++mi)
#pragma unroll
    for (int j = 0; j < 4; ++j) acc2[mi][j] = f32x4{0.f,0.f,0.f,0.f};

#pragma unroll
  for (int kk = 0; kk < 8; ++kk) {
    s16x8 a[4];
#pragma unroll
    for (int mi = 0; mi < 4; ++mi)
      a[mi] = *(const s16x8*)(lds + SWZ2(mi * 16 + l15, kk * 64 + lk * 16));
    const char* wb = (const char*)W2 + kk * 32768 + lk * 16;
#pragma unroll
    for (int j = 0; j < 4; ++j) {
      s16x8 bf = *(const s16x8*)(wb + (size_t)(16 * w + 128 * j + l15) * 64);
#pragma unroll
      for (int mi = 0; mi < 4; ++mi)
        acc2[mi][j] = __builtin_amdgcn_mfma_f32_16x16x32_bf16(a[mi], bf, acc2[mi][j], 0, 0, 0);
    }
  }

  // ---- Phase 3: LSTM pointwise + mask select. acc2[mi][j]: gate j (i,f,g,o), rows mi*16+lk*4+r
  float bs[4];
#pragma unroll
  for (int j = 0; j < 4; ++j) bs[j] = biasg[128 * j + 16 * w + l15];
  const int d = 16 * w + l15;

#pragma unroll
  for (int mi = 0; mi < 4; ++mi) {
#pragma unroll
    for (int r = 0; r < 4; ++r) {
      int m = mi * 16 + lk * 4 + r;
      size_t node = (size_t)node0 + m;
      int act = tsm[node];
      float gi = acc2[mi][0][r] + bs[0];
      float gf = acc2[mi][1][r] + bs[1];
      float gg = acc2[mi][2][r] + bs[2];
      float go = acc2[mi][3][r] + bs[3];
      float i_ = fsig(gi), f_ = fsig(gf), o_ = fsig(go);
      float g_ = ftanh(gg);
      float co = cvp[node * 128 + d];
      float ho = hvp[node * 128 + d];
      float cn = f_ * co + i_ * g_;
      float hn = o_ * ftanh(cn);
      hvo[node * 128 + d] = act ? hn : ho;
      cvo[node * 128 + d] = act ? cn : co;
    }
  }
}

extern "C" void kernel_launch(void* const* d_in, const int* in_sizes, int n_in,
                              void* d_out, int out_size, void* d_ws, size_t ws_size,
                              hipStream_t stream) {
  const float* Hv   = (const float*)d_in[0];
  const float* hvv  = (const float*)d_in[1];
  const float* xv   = (const float*)d_in[2];
  const float* hvp  = (const float*)d_in[3];
  const float* cvp  = (const float*)d_in[4];
  const int*   tsm  = (const int*)d_in[5];
  const float* Wpos = (const float*)d_in[6];
  const float* bpos = (const float*)d_in[7];
  const float* Whid = (const float*)d_in[8];
  const float* bhid = (const float*)d_in[9];
  const float* Wih  = (const float*)d_in[10];
  const float* bih  = (const float*)d_in[11];
  const float* Whh  = (const float*)d_in[12];
  const float* bhh  = (const float*)d_in[13];

  unsigned short* wsWh2 = (unsigned short*)d_ws;   // 32768 bf16
  unsigned short* wsW2  = wsWh2 + 32768;           // 131072 bf16
  float* wsBias = (float*)(wsW2 + 131072);         // 512 f32

  prep_kernel<<<512, 256, 0, stream>>>(Whid, Wih, Whh, bih, bhh,
                                       wsWh2, wsW2, wsBias);

  float* hvo = (float*)d_out;
  float* cvo = hvo + (size_t)N_NODES * 128;
  node_rnn_kernel<<<N_NODES / BM, NTHREADS, 0, stream>>>(
      Hv, hvv, xv, hvp, cvp, tsm, Wpos, bpos, bhid,
      wsWh2, wsW2, wsBias, hvo, cvo);
}